// Round 1
// baseline (6072.819 us; speedup 1.0000x reference)
//
#include <hip/hip_runtime.h>

// Problem dims (fixed)
#define NB 4096   // B
#define NL 7      // L
#define ND 1024   // D
#define NH 1024   // H
#define NT 6      // T
#define NSTEP 5   // effective scan steps (t = 0..4; step 5's carry is unused)

// ---------------- threefry2x32 (JAX-compatible, 20 rounds) ----------------
__device__ __forceinline__ unsigned rotl32(unsigned x, int r) {
  return (x << r) | (x >> (32 - r));
}

__device__ __forceinline__ void threefry2x32(unsigned k0, unsigned k1,
                                             unsigned x0, unsigned x1,
                                             unsigned& o0, unsigned& o1) {
  unsigned ks2 = k0 ^ k1 ^ 0x1BD11BDAu;
#define TFR(R) { x0 += x1; x1 = rotl32(x1, (R)); x1 ^= x0; }
  x0 += k0; x1 += k1;
  TFR(13) TFR(15) TFR(26) TFR(6)
  x0 += k1; x1 += ks2 + 1u;
  TFR(17) TFR(29) TFR(16) TFR(24)
  x0 += ks2; x1 += k0 + 2u;
  TFR(13) TFR(15) TFR(26) TFR(6)
  x0 += k0; x1 += k1 + 3u;
  TFR(17) TFR(29) TFR(16) TFR(24)
  x0 += k1; x1 += ks2 + 4u;
  TFR(13) TFR(15) TFR(26) TFR(6)
  x0 += ks2; x1 += k0 + 5u;
#undef TFR
  o0 = x0; o1 = x1;
}

// ---------------- shared 64x64 fp32 tile core ----------------
__device__ __forceinline__ void tile_compute(const float (*As)[68],
                                             const float (*Bs)[68],
                                             float acc[4][4], int tx, int ty) {
#pragma unroll
  for (int kk = 0; kk < 16; ++kk) {
    float4 a  = *(const float4*)&As[kk][ty * 4];
    float4 bb = *(const float4*)&Bs[kk][tx * 4];
    acc[0][0] += a.x * bb.x; acc[0][1] += a.x * bb.y; acc[0][2] += a.x * bb.z; acc[0][3] += a.x * bb.w;
    acc[1][0] += a.y * bb.x; acc[1][1] += a.y * bb.y; acc[1][2] += a.y * bb.z; acc[1][3] += a.y * bb.w;
    acc[2][0] += a.z * bb.x; acc[2][1] += a.z * bb.y; acc[2][2] += a.z * bb.z; acc[2][3] += a.z * bb.w;
    acc[3][0] += a.w * bb.x; acc[3][1] += a.w * bb.y; acc[3][2] += a.w * bb.z; acc[3][3] += a.w * bb.w;
  }
}

#define TILE_DECLS \
  __shared__ float As[16][68]; \
  __shared__ float Bs[16][68]; \
  float acc[4][4] = {}; \
  const int tid = threadIdx.x; \
  const int tx = tid & 15, ty = tid >> 4; \
  const int row0 = blockIdx.y * 64, col0 = blockIdx.x * 64; \
  const int lm = tid >> 2; \
  const int lk4 = (tid & 3) * 4;

#define STORE_AS(av) { As[lk4+0][lm]=(av).x; As[lk4+1][lm]=(av).y; As[lk4+2][lm]=(av).z; As[lk4+3][lm]=(av).w; }
#define STORE_BS(bv) { Bs[lk4+0][lm]=(bv).x; Bs[lk4+1][lm]=(bv).y; Bs[lk4+2][lm]=(bv).z; Bs[lk4+3][lm]=(bv).w; }

// ---------------- G1: edge_all[t,b,:] for t=0..4 ----------------
// edge = (tt==0) ? h@Wh^T + v@Wv^T : h@Wsh^T + v@Wsv^T, expressed as a
// K=4096 GEMM over 4 segments with inactive segments contributing exact zeros.
__global__ __launch_bounds__(256) void g1_edge(
    const float* __restrict__ enc, const int* __restrict__ xes,
    const float* __restrict__ Wh, const float* __restrict__ Wv,
    const float* __restrict__ Wsh, const float* __restrict__ Wsv,
    float* __restrict__ edge_all) {
  TILE_DECLS
  const int r = row0 + lm;          // r = t*NB + b, r < 20480
  const int b = r & (NB - 1);
  const int t = r >> 12;
  const int hi = xes[(b * NT + t) * 3 + 0];
  const int vi = xes[(b * NT + t) * 3 + 1];
  const int tt = xes[(b * NT + t) * 3 + 2];

  for (int seg = 0; seg < 4; ++seg) {
    const float* Wp = (seg == 0) ? Wh : (seg == 1) ? Wv : (seg == 2) ? Wsh : Wsv;
    const int li = (seg & 1) ? vi : hi;
    const bool act = ((seg >> 1) == 0) == (tt == 0);
    const float* arow = enc + (((size_t)b * NL + li) << 10);
    const float* brow = Wp + ((size_t)(col0 + lm) << 10);
    for (int k0 = 0; k0 < ND; k0 += 16) {
      float4 av = make_float4(0.f, 0.f, 0.f, 0.f);
      if (act) av = *(const float4*)(arow + k0 + lk4);
      STORE_AS(av)
      float4 bv = *(const float4*)(brow + k0 + lk4);
      STORE_BS(bv)
      __syncthreads();
      tile_compute(As, Bs, acc, tx, ty);
      __syncthreads();
    }
  }
#pragma unroll
  for (int i = 0; i < 4; ++i) {
    float4 v = make_float4(acc[i][0], acc[i][1], acc[i][2], acc[i][3]);
    *(float4*)(edge_all + ((size_t)(row0 + ty * 4 + i) << 10) + col0 + tx * 4) = v;
  }
}

// ---------------- G2: st[b,h] = max(0, max_t (edge_all @ We^T)) ----------------
__global__ __launch_bounds__(256) void g2_stmax(
    const float* __restrict__ edge_all, const float* __restrict__ We,
    unsigned* __restrict__ st) {
  TILE_DECLS
  const float* arow = edge_all + ((size_t)(row0 + lm) << 10);
  const float* brow = We + ((size_t)(col0 + lm) << 10);
  for (int k0 = 0; k0 < NH; k0 += 16) {
    float4 av = *(const float4*)(arow + k0 + lk4);
    STORE_AS(av)
    float4 bv = *(const float4*)(brow + k0 + lk4);
    STORE_BS(bv)
    __syncthreads();
    tile_compute(As, Bs, acc, tx, ty);
    __syncthreads();
  }
#pragma unroll
  for (int i = 0; i < 4; ++i) {
    const int r = row0 + ty * 4 + i;
    const int b = r & (NB - 1);
#pragma unroll
    for (int j = 0; j < 4; ++j) {
      // clamp at 0 first => uint-bit compare is order-preserving (all >= 0)
      unsigned val = __float_as_uint(fmaxf(acc[i][j], 0.f));
      atomicMax(&st[(size_t)b * NH + col0 + tx * 4 + j], val);
    }
  }
}

// ---------------- G3/G4: C = A @ Bw^T + bias (A optionally gathered from enc) --------
__global__ __launch_bounds__(256) void gemm_bias(
    const float* __restrict__ A, const int* __restrict__ gidx,
    const float* __restrict__ enc, const float* __restrict__ Bw,
    const float* __restrict__ bias, float* __restrict__ C) {
  TILE_DECLS
  const int r = row0 + lm;
  const float* arow = gidx ? (enc + (((size_t)r * NL + gidx[r]) << 10))
                           : (A + ((size_t)r << 10));
  const float* brow = Bw + ((size_t)(col0 + lm) << 10);
  for (int k0 = 0; k0 < ND; k0 += 16) {
    float4 av = *(const float4*)(arow + k0 + lk4);
    STORE_AS(av)
    float4 bv = *(const float4*)(brow + k0 + lk4);
    STORE_BS(bv)
    __syncthreads();
    tile_compute(As, Bs, acc, tx, ty);
    __syncthreads();
  }
#pragma unroll
  for (int i = 0; i < 4; ++i) {
    const int rr = row0 + ty * 4 + i;
    const int n0 = col0 + tx * 4;
    float4 v = make_float4(acc[i][0] + bias[n0 + 0], acc[i][1] + bias[n0 + 1],
                           acc[i][2] + bias[n0 + 2], acc[i][3] + bias[n0 + 3]);
    *(float4*)(C + ((size_t)rr << 10) + n0) = v;
  }
}

// ---------------- G5: fused ctx GEMM + tanh + V4 reduction -> att[B,28] ----------
// Row r = b*7+l of enc viewed [B*L, D]; col n = k*1024+h of Wc viewed [4096, 1024].
__global__ __launch_bounds__(256) void g5_att(
    const float* __restrict__ enc, const float* __restrict__ Wc,
    const float* __restrict__ bc, const float* __restrict__ V4,
    const float* __restrict__ inp, float* __restrict__ att) {
  TILE_DECLS
  __shared__ float red[64][17];
  const float* arow = enc + ((size_t)(row0 + lm) << 10);
  const float* brow = Wc + ((size_t)(col0 + lm) << 10);
  for (int k0 = 0; k0 < ND; k0 += 16) {
    float4 av = *(const float4*)(arow + k0 + lk4);
    STORE_AS(av)
    float4 bv = *(const float4*)(brow + k0 + lk4);
    STORE_BS(bv)
    __syncthreads();
    tile_compute(As, Bs, acc, tx, ty);
    __syncthreads();
  }
  const int kq = col0 >> 10;  // which of the 4 heads (64-col tile never straddles)
#pragma unroll
  for (int i = 0; i < 4; ++i) {
    const int r = row0 + ty * 4 + i;
    const int bb = r / NL;
    float s = 0.f;
#pragma unroll
    for (int j = 0; j < 4; ++j) {
      const int h = (col0 + tx * 4 + j) & (NH - 1);
      float y = tanhf(acc[i][j] + inp[(size_t)bb * NH + h] + bc[kq * NH + h]);
      s += V4[kq * NH + h] * y;
    }
    red[ty * 4 + i][tx] = s;
  }
  __syncthreads();
  if (tid < 64) {
    float s = 0.f;
#pragma unroll
    for (int x = 0; x < 16; ++x) s += red[tid][x];
    const int r = row0 + tid;
    const int bb = r / NL;
    const int l = r - bb * NL;
    atomicAdd(&att[bb * 28 + kq * NL + l], s);
  }
}

// ---------------- elementwise: query = relu(relu(relu(e4+st)+lin)+lin) ----------
__global__ __launch_bounds__(256) void k_query(
    const float* __restrict__ edge_all, const float* __restrict__ st,
    const float* __restrict__ lin, float* __restrict__ query) {
  const size_t i = (size_t)blockIdx.x * 256 + threadIdx.x;  // < NB*NH
  float e4 = edge_all[(size_t)4 * NB * NH + i];
  float qt = fmaxf(e4 + st[i], 0.f);
  float l = lin[i];
  float q = fmaxf(qt + l, 0.f);
  q = fmaxf(q + l, 0.f);
  query[i] = q;
}

// ---------------- att finish: mask -> -inf -> 10*tanh ----------------
__global__ __launch_bounds__(256) void k_finish(
    float* __restrict__ att, const int* __restrict__ mask) {
  const int i = blockIdx.x * 256 + threadIdx.x;  // < NB*28
  const int b = i / 28;
  const int j = i - b * 28;
  const int l = j % NL;
  float v = att[i];
  att[i] = (mask[b * NL + l] != 0) ? (10.f * tanhf(v)) : -10.f;
}

// ---------------- per-column (over B) softmax stats ----------------
__global__ __launch_bounds__(256) void k_colstats(
    const float* __restrict__ att, float* __restrict__ Mv, float* __restrict__ Sv) {
  const int j = blockIdx.x;  // 0..27
  const int tid = threadIdx.x;
  __shared__ float sm[256];
  float m = -INFINITY;
  for (int b = tid; b < NB; b += 256) m = fmaxf(m, att[b * 28 + j]);
  sm[tid] = m;
  __syncthreads();
  for (int s = 128; s > 0; s >>= 1) {
    if (tid < s) sm[tid] = fmaxf(sm[tid], sm[tid + s]);
    __syncthreads();
  }
  const float M = sm[0];
  __syncthreads();
  float sum = 0.f;
  for (int b = tid; b < NB; b += 256) sum += expf(att[b * 28 + j] - M);
  sm[tid] = sum;
  __syncthreads();
  for (int s = 128; s > 0; s >>= 1) {
    if (tid < s) sm[tid] += sm[tid + s];
    __syncthreads();
  }
  if (tid == 0) { Mv[j] = M; Sv[j] = sm[0]; }
}

// ---------------- sampling: gumbel-argmax, p, mask_out ----------------
// JAX partitionable threefry: bits[m] = o0 ^ o1 of threefry2x32((0,42),(0,m)).
// (Fallback candidate if indices mismatch: original split-iota mapping.)
__global__ __launch_bounds__(256) void k_sample(
    const float* __restrict__ att, const float* __restrict__ Mv,
    const float* __restrict__ Sv, const int* __restrict__ mask,
    float* __restrict__ out) {
  const int b = blockIdx.x * 256 + threadIdx.x;
  if (b >= NB) return;
  const float TINY = 1.17549435e-38f;
  float best = -INFINITY;
  int bj = 0;
  float bestAlpha = 0.f;
  for (int j = 0; j < 28; ++j) {
    unsigned o0, o1;
    threefry2x32(0u, 42u, 0u, (unsigned)(b * 28 + j), o0, o1);
    unsigned bits = o0 ^ o1;
    float u = __uint_as_float((bits >> 9) | 0x3f800000u) - 1.0f;
    u = fmaxf(TINY, u + TINY);           // uniform in [tiny, 1)
    float g = -logf(-logf(u));           // gumbel
    float alpha = expf(att[b * 28 + j] - Mv[j]) / Sv[j];
    float y = logf(alpha) + g;
    if (y > best) { best = y; bj = j; bestAlpha = alpha; }
  }
  out[b] = (float)bj;              // indices
  out[NB + b] = bestAlpha;         // p
  const int* mrow = mask + b * NL;
#pragma unroll
  for (int l = 0; l < NL; ++l)
    out[2 * NB + (size_t)b * NL + l] = (float)(mrow[l] - ((l == bj) ? 1 : 0));
}

extern "C" void kernel_launch(void* const* d_in, const int* in_sizes, int n_in,
                              void* d_out, int out_size, void* d_ws, size_t ws_size,
                              hipStream_t stream) {
  const float* enc  = (const float*)d_in[0];
  const int*   xes  = (const int*)d_in[1];
  const int*   idx  = (const int*)d_in[2];
  const int*   mask = (const int*)d_in[3];
  const float* Wq   = (const float*)d_in[4];
  const float* bq   = (const float*)d_in[5];
  const float* Wc   = (const float*)d_in[6];
  const float* bc   = (const float*)d_in[7];
  const float* V4   = (const float*)d_in[8];
  const float* Wi   = (const float*)d_in[9];
  const float* bi   = (const float*)d_in[10];
  const float* Wh   = (const float*)d_in[11];
  const float* Wv   = (const float*)d_in[12];
  const float* Wsh  = (const float*)d_in[13];
  const float* Wsv  = (const float*)d_in[14];
  const float* We   = (const float*)d_in[15];
  (void)in_sizes; (void)n_in; (void)out_size; (void)ws_size;

  // workspace layout (~151.5 MB total)
  float* edge_all = (float*)d_ws;                          // [5*NB, NH]
  float* st       = edge_all + (size_t)NSTEP * NB * NH;    // [NB, NH] (uint-bit floats)
  float* lin      = st + (size_t)NB * NH;                  // [NB, NH]
  float* query    = lin + (size_t)NB * NH;                 // [NB, NH]
  float* inp      = query + (size_t)NB * NH;               // [NB, NH]
  float* att      = inp + (size_t)NB * NH;                 // [NB, 28]
  float* Mv       = att + (size_t)NB * 28;                 // [28]
  float* Sv       = Mv + 28;                               // [28]
  float* out      = (float*)d_out;

  hipMemsetAsync(st, 0, (size_t)NB * NH * sizeof(float), stream);
  hipMemsetAsync(att, 0, (size_t)NB * 28 * sizeof(float), stream);

  dim3 blk(256);
  // edges for t=0..4 (M=20480, N=1024, K=4096 incl. zero segments)
  g1_edge<<<dim3(16, 320), blk, 0, stream>>>(enc, xes, Wh, Wv, Wsh, Wsv, edge_all);
  // lin = gather(enc, idx) @ Wi^T + bi
  gemm_bias<<<dim3(16, 64), blk, 0, stream>>>(nullptr, idx, enc, Wi, bi, lin);
  // st = max(0, max_t edge@We^T)
  g2_stmax<<<dim3(16, 320), blk, 0, stream>>>(edge_all, We, (unsigned*)st);
  // query
  k_query<<<dim3((NB * NH) / 256), blk, 0, stream>>>(edge_all, st, lin, query);
  // inp = query @ Wq^T + bq
  gemm_bias<<<dim3(16, 64), blk, 0, stream>>>(query, nullptr, enc, Wq, bq, inp);
  // att partial sums (fused ctx GEMM + tanh + V4 reduce)
  g5_att<<<dim3(64, 448), blk, 0, stream>>>(enc, Wc, bc, V4, inp, att);
  // mask + 10*tanh
  k_finish<<<dim3((NB * 28) / 256), blk, 0, stream>>>(att, mask);
  // column softmax stats over B
  k_colstats<<<dim3(28), blk, 0, stream>>>(att, Mv, Sv);
  // gumbel-argmax sampling + outputs
  k_sample<<<dim3(NB / 256), blk, 0, stream>>>(att, Mv, Sv, mask, out);
}